// Round 12
// baseline (171.889 us; speedup 1.0000x reference)
//
#include <hip/hip_runtime.h>

#define N_SEQ 4096
#define N_FFT 8192
#define LAYERS 3
#define FT 512                 // threads per FFT block
#define PIDX(i) ((i) + ((i) >> 5))   // +1 word per 32 -> all passes 2-way (free)

// =============== radix-16 pass: two DIF stages (M then M/4) in registers ===============
template<int M>
__device__ inline void pass16_fwd(float* re, float* im, int tid)
{
    const int Q = M >> 4;
    const int j = tid & (Q - 1);
    const int G = tid / Q;
    const int base = G * M + j;
    const float KR[4] = {1.f, 0.9238795325f, 0.7071067812f, 0.3826834324f};
    const float KI[4] = {0.f, -0.3826834324f, -0.7071067812f, -0.9238795325f};
    float xr[4][4], xi[4][4];
#pragma unroll
    for (int a = 0; a < 4; ++a)
#pragma unroll
        for (int b = 0; b < 4; ++b) {
            int idx = PIDX(base + a * (M >> 2) + b * Q);
            xr[a][b] = re[idx]; xi[a][b] = im[idx];
        }
    float cj, sj;
    __sincosf(-6.283185307179586f / (float)M * (float)j, &sj, &cj);
#pragma unroll
    for (int b = 0; b < 4; ++b) {
        float c1 = cj * KR[b] - sj * KI[b];
        float s1 = cj * KI[b] + sj * KR[b];
        float c2 = c1 * c1 - s1 * s1, s2 = 2.f * c1 * s1;
        float c3 = c2 * c1 - s2 * s1, s3 = c2 * s1 + s2 * c1;
        float ar = xr[0][b] + xr[2][b], ai = xi[0][b] + xi[2][b];
        float br = xr[0][b] - xr[2][b], bi = xi[0][b] - xi[2][b];
        float cr = xr[1][b] + xr[3][b], ci = xi[1][b] + xi[3][b];
        float dr = xi[1][b] - xi[3][b], di = -(xr[1][b] - xr[3][b]);
        xr[0][b] = ar + cr;               xi[0][b] = ai + ci;
        float t1r = br + dr, t1i = bi + di;
        xr[1][b] = t1r * c1 - t1i * s1;   xi[1][b] = t1r * s1 + t1i * c1;
        float t2r = ar - cr, t2i = ai - ci;
        xr[2][b] = t2r * c2 - t2i * s2;   xi[2][b] = t2r * s2 + t2i * c2;
        float t3r = br - dr, t3i = bi - di;
        xr[3][b] = t3r * c3 - t3i * s3;   xi[3][b] = t3r * s3 + t3i * c3;
    }
    {
        float e1c = cj * cj - sj * sj, e1s = 2.f * cj * sj;      // W^{2j}
        float c1 = e1c * e1c - e1s * e1s, s1 = 2.f * e1c * e1s;  // W^{4j}
        float c2 = c1 * c1 - s1 * s1, s2 = 2.f * c1 * s1;
        float c3 = c2 * c1 - s2 * s1, s3 = c2 * s1 + s2 * c1;
#pragma unroll
        for (int a = 0; a < 4; ++a) {
            float ar = xr[a][0] + xr[a][2], ai = xi[a][0] + xi[a][2];
            float br = xr[a][0] - xr[a][2], bi = xi[a][0] - xi[a][2];
            float cr = xr[a][1] + xr[a][3], ci = xi[a][1] + xi[a][3];
            float dr = xi[a][1] - xi[a][3], di = -(xr[a][1] - xr[a][3]);
            xr[a][0] = ar + cr;               xi[a][0] = ai + ci;
            float t1r = br + dr, t1i = bi + di;
            xr[a][1] = t1r * c1 - t1i * s1;   xi[a][1] = t1r * s1 + t1i * c1;
            float t2r = ar - cr, t2i = ai - ci;
            xr[a][2] = t2r * c2 - t2i * s2;   xi[a][2] = t2r * s2 + t2i * c2;
            float t3r = br - dr, t3i = bi - di;
            xr[a][3] = t3r * c3 - t3i * s3;   xi[a][3] = t3r * s3 + t3i * c3;
        }
    }
#pragma unroll
    for (int a = 0; a < 4; ++a)
#pragma unroll
        for (int b = 0; b < 4; ++b) {
            int idx = PIDX(base + a * (M >> 2) + b * Q);
            re[idx] = xr[a][b]; im[idx] = xi[a][b];
        }
}

template<int M>
__device__ inline void pass16_inv(float* re, float* im, int tid)
{
    const int Q = M >> 4;
    const int j = tid & (Q - 1);
    const int G = tid / Q;
    const int base = G * M + j;
    const float KR[4] = {1.f, 0.9238795325f, 0.7071067812f, 0.3826834324f};
    const float KI[4] = {0.f, 0.3826834324f, 0.7071067812f, 0.9238795325f};   // conj
    float xr[4][4], xi[4][4];
#pragma unroll
    for (int a = 0; a < 4; ++a)
#pragma unroll
        for (int b = 0; b < 4; ++b) {
            int idx = PIDX(base + a * (M >> 2) + b * Q);
            xr[a][b] = re[idx]; xi[a][b] = im[idx];
        }
    float cj, sj;
    __sincosf(6.283185307179586f / (float)M * (float)j, &sj, &cj);
    {
        float e1c = cj * cj - sj * sj, e1s = 2.f * cj * sj;
        float c1 = e1c * e1c - e1s * e1s, s1 = 2.f * e1c * e1s;
        float c2 = c1 * c1 - s1 * s1, s2 = 2.f * c1 * s1;
        float c3 = c2 * c1 - s2 * s1, s3 = c2 * s1 + s2 * c1;
#pragma unroll
        for (int a = 0; a < 4; ++a) {
            float t0r = xr[a][0], t0i = xi[a][0];
            float t1r = xr[a][1] * c1 - xi[a][1] * s1, t1i = xr[a][1] * s1 + xi[a][1] * c1;
            float t2r = xr[a][2] * c2 - xi[a][2] * s2, t2i = xr[a][2] * s2 + xi[a][2] * c2;
            float t3r = xr[a][3] * c3 - xi[a][3] * s3, t3i = xr[a][3] * s3 + xi[a][3] * c3;
            float pr = t0r + t2r, pi = t0i + t2i;
            float qr = t0r - t2r, qi = t0i - t2i;
            float rr = t1r + t3r, ri = t1i + t3i;
            float sr = -(t1i - t3i), si = t1r - t3r;
            xr[a][0] = pr + rr; xi[a][0] = pi + ri;
            xr[a][1] = qr + sr; xi[a][1] = qi + si;
            xr[a][2] = pr - rr; xi[a][2] = pi - ri;
            xr[a][3] = qr - sr; xi[a][3] = qi - si;
        }
    }
#pragma unroll
    for (int b = 0; b < 4; ++b) {
        float c1 = cj * KR[b] - sj * KI[b];
        float s1 = cj * KI[b] + sj * KR[b];
        float c2 = c1 * c1 - s1 * s1, s2 = 2.f * c1 * s1;
        float c3 = c2 * c1 - s2 * s1, s3 = c2 * s1 + s2 * c1;
        float t0r = xr[0][b], t0i = xi[0][b];
        float t1r = xr[1][b] * c1 - xi[1][b] * s1, t1i = xr[1][b] * s1 + xi[1][b] * c1;
        float t2r = xr[2][b] * c2 - xi[2][b] * s2, t2i = xr[2][b] * s2 + xi[2][b] * c2;
        float t3r = xr[3][b] * c3 - xi[3][b] * s3, t3i = xr[3][b] * s3 + xi[3][b] * c3;
        float pr = t0r + t2r, pi = t0i + t2i;
        float qr = t0r - t2r, qi = t0i - t2i;
        float rr = t1r + t3r, ri = t1i + t3i;
        float sr = -(t1i - t3i), si = t1r - t3r;
        xr[0][b] = pr + rr; xi[0][b] = pi + ri;
        xr[1][b] = qr + sr; xi[1][b] = qi + si;
        xr[2][b] = pr - rr; xi[2][b] = pi - ri;
        xr[3][b] = qr - sr; xi[3][b] = qi - si;
    }
#pragma unroll
    for (int a = 0; a < 4; ++a)
#pragma unroll
        for (int b = 0; b < 4; ++b) {
            int idx = PIDX(base + a * (M >> 2) + b * Q);
            re[idx] = xr[a][b]; im[idx] = xi[a][b];
        }
}

// ======= radix-8 tail (stage m=8 + r2), contiguous 8 points, constant twiddles =======
__device__ inline void fwd8(float* zr, float* zi, int o)
{
    const float R = 0.70710678118654752f;
    {
        float ar = zr[o] + zr[o+4], ai = zi[o] + zi[o+4];
        float br = zr[o] - zr[o+4], bi = zi[o] - zi[o+4];
        float cr = zr[o+2] + zr[o+6], ci = zi[o+2] + zi[o+6];
        float dr = zi[o+2] - zi[o+6], di = -(zr[o+2] - zr[o+6]);
        zr[o]   = ar + cr; zi[o]   = ai + ci;
        zr[o+2] = br + dr; zi[o+2] = bi + di;
        zr[o+4] = ar - cr; zi[o+4] = ai - ci;
        zr[o+6] = br - dr; zi[o+6] = bi - di;
    }
    {
        float ar = zr[o+1] + zr[o+5], ai = zi[o+1] + zi[o+5];
        float br = zr[o+1] - zr[o+5], bi = zi[o+1] - zi[o+5];
        float cr = zr[o+3] + zr[o+7], ci = zi[o+3] + zi[o+7];
        float dr = zi[o+3] - zi[o+7], di = -(zr[o+3] - zr[o+7]);
        zr[o+1] = ar + cr; zi[o+1] = ai + ci;
        float t1r = br + dr, t1i = bi + di;
        zr[o+3] = R * (t1r + t1i); zi[o+3] = R * (t1i - t1r);
        float t2r = ar - cr, t2i = ai - ci;
        zr[o+5] = t2i;  zi[o+5] = -t2r;
        float t3r = br - dr, t3i = bi - di;
        zr[o+7] = R * (t3i - t3r); zi[o+7] = -R * (t3r + t3i);
    }
#pragma unroll
    for (int p = 0; p < 8; p += 2) {
        float ur = zr[o+p], ui = zi[o+p], vr = zr[o+p+1], vi = zi[o+p+1];
        zr[o+p]   = ur + vr; zi[o+p]   = ui + vi;
        zr[o+p+1] = ur - vr; zi[o+p+1] = ui - vi;
    }
}

__device__ inline void inv8(float* zr, float* zi, int o)
{
    const float R = 0.70710678118654752f;
#pragma unroll
    for (int p = 0; p < 8; p += 2) {
        float ur = zr[o+p], ui = zi[o+p], vr = zr[o+p+1], vi = zi[o+p+1];
        zr[o+p]   = ur + vr; zi[o+p]   = ui + vi;
        zr[o+p+1] = ur - vr; zi[o+p+1] = ui - vi;
    }
    {
        float t0r = zr[o],   t0i = zi[o];
        float t1r = zr[o+2], t1i = zi[o+2];
        float t2r = zr[o+4], t2i = zi[o+4];
        float t3r = zr[o+6], t3i = zi[o+6];
        float pr = t0r + t2r, pi = t0i + t2i;
        float qr = t0r - t2r, qi = t0i - t2i;
        float rr = t1r + t3r, ri = t1i + t3i;
        float sr = -(t1i - t3i), si = t1r - t3r;
        zr[o]   = pr + rr; zi[o]   = pi + ri;
        zr[o+2] = qr + sr; zi[o+2] = qi + si;
        zr[o+4] = pr - rr; zi[o+4] = pi - ri;
        zr[o+6] = qr - sr; zi[o+6] = qi - si;
    }
    {
        float t0r = zr[o+1], t0i = zi[o+1];
        float yr = zr[o+3], yi = zi[o+3];
        float t1r = R * (yr - yi), t1i = R * (yr + yi);
        yr = zr[o+5]; yi = zi[o+5];
        float t2r = -yi, t2i = yr;
        yr = zr[o+7]; yi = zi[o+7];
        float t3r = -R * (yr + yi), t3i = R * (yr - yi);
        float pr = t0r + t2r, pi = t0i + t2i;
        float qr = t0r - t2r, qi = t0i - t2i;
        float rr = t1r + t3r, ri = t1i + t3i;
        float sr = -(t1i - t3i), si = t1r - t3r;
        zr[o+1] = pr + rr; zi[o+1] = pi + ri;
        zr[o+3] = qr + sr; zi[o+3] = qi + si;
        zr[o+5] = pr - rr; zi[o+5] = pi - ri;
        zr[o+7] = qr - sr; zi[o+7] = qi - si;
    }
}

// ============ prep: [blocks 0..1023] RPE (32 pos x 1-of-4 chunks) -> a_t
//              [blocks 1024..2047] transpose one batch plane -> xt_re / xt_im ============
// LESSON R11 (final form): prep was latency-bound at 1 RPE block/CU (VALUBusy 10%,
// occ 12%). Fix = block-level TLP: 1024 RPE blocks (hidden chain recomputed x4,
// +0.3 GFLOP) + LDS union shrunk to 16.6 KB (transpose handles ONE plane per
// block, xt split into re/im planes) -> 4 RPE blocks/CU co-resident, 16 waves/CU.
__global__ __launch_bounds__(256, 2) void prep_kernel(
    const float* __restrict__ x,
    const float* __restrict__ w_in, const float* __restrict__ b_in,
    const float* __restrict__ w_hid, const float* __restrict__ b_hid,
    const float* __restrict__ w_out, const float* __restrict__ b_out,
    float* __restrict__ a_t, float* __restrict__ xt_re, float* __restrict__ xt_im)
{
    __shared__ __align__(16) char smem[16640];
    const int tid = threadIdx.x;

    if (blockIdx.x >= 1024) {
        // ---- transpose one plane: x[b,h,:,:] -> xt_plane[h*64+d][n] ----
        float (*t)[65] = (float (*)[65])smem;
        int bb = blockIdx.x - 1024;
        int b  = bb >> 9;            // batch 0/1
        int h  = (bb >> 6) & 7;
        int nb = bb & 63;
        int lx = tid & 63;
        int ly = tid >> 6;           // 0..3
        const float* src = x + ((size_t)(b * 8 + h) * N_SEQ + nb * 64) * 64;
        float* plane = b ? xt_im : xt_re;
        for (int r = ly; r < 64; r += 4)
            t[r][lx] = src[r * 64 + lx];
        __syncthreads();
        for (int r = ly; r < 64; r += 4)
            plane[(size_t)(h * 64 + r) * N_SEQ + nb * 64 + lx] = t[lx][r];
        return;
    }

    // LDS: ubuf[j=64][pos stride 36] transposed activations (9216 B);
    //      sums[pos=32][9] RMS partials (1152 B)
    float (*ubuf)[36] = (float (*)[36])smem;
    float (*sums)[9]  = (float (*)[9])(smem + 9216);
    const int pt = blockIdx.x >> 2;       // pos-tile
    const int co = blockIdx.x & 3;        // this block's output chunk (128 outs)
    const int pos0 = pt * 32;

    // ---- hidden chain (recomputed per co): thread = (p = tid&31, fp = tid>>5) ----
    {
        const int p  = tid & 31;
        const int fp = tid >> 5;
        const int pos = pos0 + p;
        float v;
        if (pos == 0 || pos == N_SEQ) v = 1.0f;
        else if (pos < N_SEQ)         v = 1.0f / (float)(pos + 1);
        else                          v = -1.0f / (float)(2 * N_SEQ + 1 - pos);

        float h[8];
#pragma unroll
        for (int i = 0; i < 8; ++i) {
            int f = fp * 8 + i;
            h[i] = v * w_in[f] + b_in[f];
        }
        for (int L = 0; L <= LAYERS; ++L) {
            float s = 0.f;
#pragma unroll
            for (int i = 0; i < 8; ++i) s += h[i] * h[i];
            sums[p][fp] = s;
            __syncthreads();          // also orders prior j-loop's ubuf reads
            float tot = 0.f;
#pragma unroll
            for (int g = 0; g < 8; ++g) tot += sums[p][g];
            float r = rsqrtf(tot * (1.f / 64.f) + 1e-8f);
#pragma unroll
            for (int i = 0; i < 8; ++i)
                ubuf[fp * 8 + i][p] = fmaxf(h[i] * r, 0.f);   // transposed [j][pos]
            __syncthreads();
            if (L == LAYERS) break;
            float acc[8];
#pragma unroll
            for (int i = 0; i < 8; ++i) acc[i] = b_hid[L * 64 + fp * 8 + i];
            const float* wb = w_hid + L * 4096 + fp * 8;
#pragma unroll 4
            for (int j = 0; j < 64; ++j) {
                float uj = ubuf[j][p];
                float4 w0 = *(const float4*)(wb + j * 64);
                float4 w1 = *(const float4*)(wb + j * 64 + 4);
                acc[0] = fmaf(uj, w0.x, acc[0]); acc[1] = fmaf(uj, w0.y, acc[1]);
                acc[2] = fmaf(uj, w0.z, acc[2]); acc[3] = fmaf(uj, w0.w, acc[3]);
                acc[4] = fmaf(uj, w1.x, acc[4]); acc[5] = fmaf(uj, w1.y, acc[5]);
                acc[6] = fmaf(uj, w1.z, acc[6]); acc[7] = fmaf(uj, w1.w, acc[7]);
            }
#pragma unroll
            for (int i = 0; i < 8; ++i) h[i] = acc[i];
        }
    }

    // ---- out GEMM (this block's 128 outputs): thread = (p4 = tid&7, of = tid>>3) ----
    {
        const int p4 = tid & 7;
        const int of = tid >> 3;
        float acc[4][4];              // [out i][pos k] = 16 regs (no spill)
#pragma unroll
        for (int i = 0; i < 4; ++i) {
            float bo = b_out[co * 128 + of * 4 + i];
#pragma unroll
            for (int k = 0; k < 4; ++k) acc[i][k] = bo;
        }
        const float* wb = w_out + co * 128 + of * 4;
#pragma unroll 4
        for (int j = 0; j < 64; ++j) {
            float4 u4 = *(const float4*)&ubuf[j][p4 * 4];
            float4 w4 = *(const float4*)(wb + j * 512);
            acc[0][0] = fmaf(u4.x, w4.x, acc[0][0]); acc[0][1] = fmaf(u4.y, w4.x, acc[0][1]);
            acc[0][2] = fmaf(u4.z, w4.x, acc[0][2]); acc[0][3] = fmaf(u4.w, w4.x, acc[0][3]);
            acc[1][0] = fmaf(u4.x, w4.y, acc[1][0]); acc[1][1] = fmaf(u4.y, w4.y, acc[1][1]);
            acc[1][2] = fmaf(u4.z, w4.y, acc[1][2]); acc[1][3] = fmaf(u4.w, w4.y, acc[1][3]);
            acc[2][0] = fmaf(u4.x, w4.z, acc[2][0]); acc[2][1] = fmaf(u4.y, w4.z, acc[2][1]);
            acc[2][2] = fmaf(u4.z, w4.z, acc[2][2]); acc[2][3] = fmaf(u4.w, w4.z, acc[2][3]);
            acc[3][0] = fmaf(u4.x, w4.w, acc[3][0]); acc[3][1] = fmaf(u4.y, w4.w, acc[3][1]);
            acc[3][2] = fmaf(u4.z, w4.w, acc[3][2]); acc[3][3] = fmaf(u4.w, w4.w, acc[3][3]);
        }
#pragma unroll
        for (int i = 0; i < 4; ++i) {
            float* dst = a_t + (size_t)(co * 128 + of * 4 + i) * N_FFT + pos0 + p4 * 4;
            *(float4*)dst = make_float4(acc[i][0], acc[i][1], acc[i][2], acc[i][3]);
        }
    }
}

// ========== conv: A-FFT (spectrum kept in regs) + z-FFT + mult + iFFT ==========
__global__ __launch_bounds__(FT, 2) void conv_kernel(const float* __restrict__ a_t,
                                                     const float* __restrict__ xt_re,
                                                     const float* __restrict__ xt_im,
                                                     float2* __restrict__ out_t2)
{
    __shared__ float re[8448];
    __shared__ float im[8448];
    const int tid = threadIdx.x;
    const int hd = blockIdx.x;
    const float JR = 0.9238795325f;        // e^{-2pi i/16}
    const float JI = -0.3826834324f;

    // ---- A forward: fused m=8192 stage (real input) ----
    {
        const float* src = a_t + (size_t)hd * N_FFT;
        float ck, sk;
        __sincosf(-6.283185307179586f / 8192.f * (float)tid, &sk, &ck);
#pragma unroll
        for (int pp = 0; pp < 4; ++pp) {
            int k = pp * FT + tid;
            float x0 = src[k], x1 = src[k + 2048], x2 = src[k + 4096], x3 = src[k + 6144];
            float ar = x0 + x2, br = x0 - x2;
            float cr = x1 + x3, e = x1 - x3;
            re[PIDX(k)] = ar + cr; im[PIDX(k)] = 0.f;
            float c1 = ck, s1 = sk;
            float c2 = c1 * c1 - s1 * s1, s2 = 2.f * c1 * s1;
            float c3 = c2 * c1 - s2 * s1, s3 = c2 * s1 + s2 * c1;
            re[PIDX(k + 2048)] = br * c1 + e * s1;  im[PIDX(k + 2048)] = br * s1 - e * c1;
            float t2r = ar - cr;
            re[PIDX(k + 4096)] = t2r * c2;          im[PIDX(k + 4096)] = t2r * s2;
            re[PIDX(k + 6144)] = br * c3 - e * s3;  im[PIDX(k + 6144)] = br * s3 + e * c3;
            float tc = ck * JR - sk * JI; sk = ck * JI + sk * JR; ck = tc;  // W^{k+512}
        }
    }
    __syncthreads();
    pass16_fwd<2048>(re, im, tid);
    __syncthreads();
    pass16_fwd<128>(re, im, tid);
    __syncthreads();
    // ---- A tail: unscaled spectrum stays in registers (1/N folded in later) ----
    float afr[16], afi[16];
    {
        const int base = tid * 16;
#pragma unroll
        for (int c = 0; c < 16; ++c) { int idx = PIDX(base + c); afr[c] = re[idx]; afi[c] = im[idx]; }
        fwd8(afr, afi, 0); fwd8(afr, afi, 8);
    }
    __syncthreads();
    // ---- Z forward: fused m=8192 stage (packed complex z = x_b0 + i x_b1, x2=x3=0) ----
    {
        const float* sre = xt_re + (size_t)hd * N_SEQ;
        const float* sim = xt_im + (size_t)hd * N_SEQ;
        float ck, sk;
        __sincosf(-6.283185307179586f / 8192.f * (float)tid, &sk, &ck);
#pragma unroll
        for (int pp = 0; pp < 4; ++pp) {
            int k = pp * FT + tid;
            float ar = sre[k],        ai = sim[k];
            float cr = sre[k + 2048], ci = sim[k + 2048];
            float dr = ci, di = -cr;
            re[PIDX(k)] = ar + cr; im[PIDX(k)] = ai + ci;
            float c1 = ck, s1 = sk;
            float c2 = c1 * c1 - s1 * s1, s2 = 2.f * c1 * s1;
            float c3 = c2 * c1 - s2 * s1, s3 = c2 * s1 + s2 * c1;
            float t1r = ar + dr, t1i = ai + di;
            re[PIDX(k + 2048)] = t1r * c1 - t1i * s1; im[PIDX(k + 2048)] = t1r * s1 + t1i * c1;
            float t2r = ar - cr, t2i = ai - ci;
            re[PIDX(k + 4096)] = t2r * c2 - t2i * s2; im[PIDX(k + 4096)] = t2r * s2 + t2i * c2;
            float t3r = ar - dr, t3i = ai - di;
            re[PIDX(k + 6144)] = t3r * c3 - t3i * s3; im[PIDX(k + 6144)] = t3r * s3 + t3i * c3;
            float tc = ck * JR - sk * JI; sk = ck * JI + sk * JR; ck = tc;
        }
    }
    __syncthreads();
    pass16_fwd<2048>(re, im, tid);
    __syncthreads();
    pass16_fwd<128>(re, im, tid);
    __syncthreads();
    {   // Z tail + pointwise (af in regs, 1/N fused) + inverse head
        const int base = tid * 16;
        float zr[16], zi[16];
#pragma unroll
        for (int c = 0; c < 16; ++c) { int idx = PIDX(base + c); zr[c] = re[idx]; zi[c] = im[idx]; }
        fwd8(zr, zi, 0); fwd8(zr, zi, 8);
        const float inv = 1.0f / (float)N_FFT;
#pragma unroll
        for (int c = 0; c < 16; ++c) {
            float xr = zr[c], xi_ = zi[c];
            zr[c] = (xr * afr[c] - xi_ * afi[c]) * inv;
            zi[c] = (xr * afi[c] + xi_ * afr[c]) * inv;
        }
        inv8(zr, zi, 0); inv8(zr, zi, 8);
#pragma unroll
        for (int c = 0; c < 16; ++c) { int idx = PIDX(base + c); re[idx] = zr[c]; im[idx] = zi[c]; }
    }
    __syncthreads();
    pass16_inv<128>(re, im, tid);
    __syncthreads();
    pass16_inv<2048>(re, im, tid);
    __syncthreads();
    {   // fused final inverse stage (m=8192): store only [0,4096)
        float2* dst = out_t2 + (size_t)hd * N_SEQ;
        float ck, sk;
        __sincosf(6.283185307179586f / 8192.f * (float)tid, &sk, &ck);
        const float JcR = 0.9238795325f, JcI = 0.3826834324f;
#pragma unroll
        for (int pp = 0; pp < 4; ++pp) {
            int k = pp * FT + tid;
            float c1 = ck, s1 = sk;
            float c2 = c1 * c1 - s1 * s1, s2 = 2.f * c1 * s1;
            float c3 = c2 * c1 - s2 * s1, s3 = c2 * s1 + s2 * c1;
            float t0r = re[PIDX(k)],        t0i = im[PIDX(k)];
            float y1r = re[PIDX(k + 2048)], y1i = im[PIDX(k + 2048)];
            float y2r = re[PIDX(k + 4096)], y2i = im[PIDX(k + 4096)];
            float y3r = re[PIDX(k + 6144)], y3i = im[PIDX(k + 6144)];
            float t1r = y1r * c1 - y1i * s1, t1i = y1r * s1 + y1i * c1;
            float t2r = y2r * c2 - y2i * s2, t2i = y2r * s2 + y2i * c2;
            float t3r = y3r * c3 - y3i * s3, t3i = y3r * s3 + y3i * c3;
            float pr = t0r + t2r, pi = t0i + t2i;
            float qr = t0r - t2r, qi = t0i - t2i;
            float rr = t1r + t3r, ri = t1i + t3i;
            float sr = -(t1i - t3i), si = t1r - t3r;
            dst[k]        = make_float2(pr + rr, pi + ri);
            dst[k + 2048] = make_float2(qr + sr, qi + si);
            float tc = ck * JcR - sk * JcI; sk = ck * JcI + sk * JcR; ck = tc;
        }
    }
}

// ========== transpose out: out_t2[hd][n] -> out (2,8,N,64) ==========
__global__ __launch_bounds__(256) void transpose_o_kernel(const float2* __restrict__ out_t2,
                                                          float* __restrict__ out)
{
    __shared__ float t0[64][65];
    __shared__ float t1[64][65];
    int h = blockIdx.x >> 6;
    int nb = blockIdx.x & 63;
    int lx = threadIdx.x & 63;
    int ly = threadIdx.x >> 6;
    for (int r = ly; r < 64; r += 4) {
        float2 v = out_t2[(size_t)(h * 64 + r) * N_SEQ + nb * 64 + lx];
        t0[r][lx] = v.x;
        t1[r][lx] = v.y;
    }
    __syncthreads();
    float* d0 = out + ((size_t)h * N_SEQ + nb * 64) * 64;
    float* d1 = out + ((size_t)(8 + h) * N_SEQ + nb * 64) * 64;
    for (int r = ly; r < 64; r += 4) {
        d0[r * 64 + lx] = t0[lx][r];
        d1[r * 64 + lx] = t1[lx][r];
    }
}

extern "C" void kernel_launch(void* const* d_in, const int* in_sizes, int n_in,
                              void* d_out, int out_size, void* d_ws, size_t ws_size,
                              hipStream_t stream)
{
    const float* x     = (const float*)d_in[0];
    const float* w_in  = (const float*)d_in[1];
    const float* b_in  = (const float*)d_in[2];
    const float* w_hid = (const float*)d_in[3];
    const float* b_hid = (const float*)d_in[4];
    const float* w_out = (const float*)d_in[5];
    const float* b_out = (const float*)d_in[6];
    float* out = (float*)d_out;

    char* ws = (char*)d_ws;
    float*  xt_re  = (float*)ws;                                // 8 MB
    float*  xt_im  = (float*)(ws + (size_t)8 * 1024 * 1024);    // 8 MB
    float*  a_t    = (float*)(ws + (size_t)16 * 1024 * 1024);   // 16 MB
    float2* out_t2 = (float2*)(ws + (size_t)32 * 1024 * 1024);  // 16 MB

    prep_kernel<<<2048, 256, 0, stream>>>(x, w_in, b_in, w_hid, b_hid, w_out, b_out,
                                          a_t, xt_re, xt_im);
    conv_kernel<<<512, FT, 0, stream>>>(a_t, xt_re, xt_im, out_t2);
    transpose_o_kernel<<<512, 256, 0, stream>>>(out_t2, out);
}

// Round 13
// 147.733 us; speedup vs baseline: 1.1635x; 1.1635x over previous
//
#include <hip/hip_runtime.h>

#define N_SEQ 4096
#define N_FFT 8192
#define LAYERS 3
#define FT 512                 // threads per FFT block
// interleaved complex LDS: float2 index, +1 float2 pad per 16 points
#define PZ(i) ((i) + ((i) >> 4))

// =============== radix-16 pass (interleaved float2 LDS) ===============
template<int M>
__device__ inline void pass16z_fwd(float2* z, int tid)
{
    const int Q = M >> 4;
    const int j = tid & (Q - 1);
    const int G = tid / Q;
    const int base = G * M + j;
    const float KR[4] = {1.f, 0.9238795325f, 0.7071067812f, 0.3826834324f};
    const float KI[4] = {0.f, -0.3826834324f, -0.7071067812f, -0.9238795325f};
    float xr[4][4], xi[4][4];
#pragma unroll
    for (int a = 0; a < 4; ++a)
#pragma unroll
        for (int b = 0; b < 4; ++b) {
            float2 v = z[PZ(base + a * (M >> 2) + b * Q)];
            xr[a][b] = v.x; xi[a][b] = v.y;
        }
    float cj, sj;
    __sincosf(-6.283185307179586f / (float)M * (float)j, &sj, &cj);
#pragma unroll
    for (int b = 0; b < 4; ++b) {
        float c1 = cj * KR[b] - sj * KI[b];
        float s1 = cj * KI[b] + sj * KR[b];
        float c2 = c1 * c1 - s1 * s1, s2 = 2.f * c1 * s1;
        float c3 = c2 * c1 - s2 * s1, s3 = c2 * s1 + s2 * c1;
        float ar = xr[0][b] + xr[2][b], ai = xi[0][b] + xi[2][b];
        float br = xr[0][b] - xr[2][b], bi = xi[0][b] - xi[2][b];
        float cr = xr[1][b] + xr[3][b], ci = xi[1][b] + xi[3][b];
        float dr = xi[1][b] - xi[3][b], di = -(xr[1][b] - xr[3][b]);
        xr[0][b] = ar + cr;               xi[0][b] = ai + ci;
        float t1r = br + dr, t1i = bi + di;
        xr[1][b] = t1r * c1 - t1i * s1;   xi[1][b] = t1r * s1 + t1i * c1;
        float t2r = ar - cr, t2i = ai - ci;
        xr[2][b] = t2r * c2 - t2i * s2;   xi[2][b] = t2r * s2 + t2i * c2;
        float t3r = br - dr, t3i = bi - di;
        xr[3][b] = t3r * c3 - t3i * s3;   xi[3][b] = t3r * s3 + t3i * c3;
    }
    {
        float e1c = cj * cj - sj * sj, e1s = 2.f * cj * sj;      // W^{2j}
        float c1 = e1c * e1c - e1s * e1s, s1 = 2.f * e1c * e1s;  // W^{4j}
        float c2 = c1 * c1 - s1 * s1, s2 = 2.f * c1 * s1;
        float c3 = c2 * c1 - s2 * s1, s3 = c2 * s1 + s2 * c1;
#pragma unroll
        for (int a = 0; a < 4; ++a) {
            float ar = xr[a][0] + xr[a][2], ai = xi[a][0] + xi[a][2];
            float br = xr[a][0] - xr[a][2], bi = xi[a][0] - xi[a][2];
            float cr = xr[a][1] + xr[a][3], ci = xi[a][1] + xi[a][3];
            float dr = xi[a][1] - xi[a][3], di = -(xr[a][1] - xr[a][3]);
            xr[a][0] = ar + cr;               xi[a][0] = ai + ci;
            float t1r = br + dr, t1i = bi + di;
            xr[a][1] = t1r * c1 - t1i * s1;   xi[a][1] = t1r * s1 + t1i * c1;
            float t2r = ar - cr, t2i = ai - ci;
            xr[a][2] = t2r * c2 - t2i * s2;   xi[a][2] = t2r * s2 + t2i * c2;
            float t3r = br - dr, t3i = bi - di;
            xr[a][3] = t3r * c3 - t3i * s3;   xi[a][3] = t3r * s3 + t3i * c3;
        }
    }
#pragma unroll
    for (int a = 0; a < 4; ++a)
#pragma unroll
        for (int b = 0; b < 4; ++b)
            z[PZ(base + a * (M >> 2) + b * Q)] = make_float2(xr[a][b], xi[a][b]);
}

template<int M>
__device__ inline void pass16z_inv(float2* z, int tid)
{
    const int Q = M >> 4;
    const int j = tid & (Q - 1);
    const int G = tid / Q;
    const int base = G * M + j;
    const float KR[4] = {1.f, 0.9238795325f, 0.7071067812f, 0.3826834324f};
    const float KI[4] = {0.f, 0.3826834324f, 0.7071067812f, 0.9238795325f};   // conj
    float xr[4][4], xi[4][4];
#pragma unroll
    for (int a = 0; a < 4; ++a)
#pragma unroll
        for (int b = 0; b < 4; ++b) {
            float2 v = z[PZ(base + a * (M >> 2) + b * Q)];
            xr[a][b] = v.x; xi[a][b] = v.y;
        }
    float cj, sj;
    __sincosf(6.283185307179586f / (float)M * (float)j, &sj, &cj);
    {
        float e1c = cj * cj - sj * sj, e1s = 2.f * cj * sj;
        float c1 = e1c * e1c - e1s * e1s, s1 = 2.f * e1c * e1s;
        float c2 = c1 * c1 - s1 * s1, s2 = 2.f * c1 * s1;
        float c3 = c2 * c1 - s2 * s1, s3 = c2 * s1 + s2 * c1;
#pragma unroll
        for (int a = 0; a < 4; ++a) {
            float t0r = xr[a][0], t0i = xi[a][0];
            float t1r = xr[a][1] * c1 - xi[a][1] * s1, t1i = xr[a][1] * s1 + xi[a][1] * c1;
            float t2r = xr[a][2] * c2 - xi[a][2] * s2, t2i = xr[a][2] * s2 + xi[a][2] * c2;
            float t3r = xr[a][3] * c3 - xi[a][3] * s3, t3i = xr[a][3] * s3 + xi[a][3] * c3;
            float pr = t0r + t2r, pi = t0i + t2i;
            float qr = t0r - t2r, qi = t0i - t2i;
            float rr = t1r + t3r, ri = t1i + t3i;
            float sr = -(t1i - t3i), si = t1r - t3r;
            xr[a][0] = pr + rr; xi[a][0] = pi + ri;
            xr[a][1] = qr + sr; xi[a][1] = qi + si;
            xr[a][2] = pr - rr; xi[a][2] = pi - ri;
            xr[a][3] = qr - sr; xi[a][3] = qi - si;
        }
    }
#pragma unroll
    for (int b = 0; b < 4; ++b) {
        float c1 = cj * KR[b] - sj * KI[b];
        float s1 = cj * KI[b] + sj * KR[b];
        float c2 = c1 * c1 - s1 * s1, s2 = 2.f * c1 * s1;
        float c3 = c2 * c1 - s2 * s1, s3 = c2 * s1 + s2 * c1;
        float t0r = xr[0][b], t0i = xi[0][b];
        float t1r = xr[1][b] * c1 - xi[1][b] * s1, t1i = xr[1][b] * s1 + xi[1][b] * c1;
        float t2r = xr[2][b] * c2 - xi[2][b] * s2, t2i = xr[2][b] * s2 + xi[2][b] * c2;
        float t3r = xr[3][b] * c3 - xi[3][b] * s3, t3i = xr[3][b] * s3 + xi[3][b] * c3;
        float pr = t0r + t2r, pi = t0i + t2i;
        float qr = t0r - t2r, qi = t0i - t2i;
        float rr = t1r + t3r, ri = t1i + t3i;
        float sr = -(t1i - t3i), si = t1r - t3r;
        xr[0][b] = pr + rr; xi[0][b] = pi + ri;
        xr[1][b] = qr + sr; xi[1][b] = qi + si;
        xr[2][b] = pr - rr; xi[2][b] = pi - ri;
        xr[3][b] = qr - sr; xi[3][b] = qi - si;
    }
#pragma unroll
    for (int a = 0; a < 4; ++a)
#pragma unroll
        for (int b = 0; b < 4; ++b)
            z[PZ(base + a * (M >> 2) + b * Q)] = make_float2(xr[a][b], xi[a][b]);
}

// ======= radix-8 tail (stage m=8 + r2), contiguous 8 points, constant twiddles =======
__device__ inline void fwd8(float* zr, float* zi, int o)
{
    const float R = 0.70710678118654752f;
    {
        float ar = zr[o] + zr[o+4], ai = zi[o] + zi[o+4];
        float br = zr[o] - zr[o+4], bi = zi[o] - zi[o+4];
        float cr = zr[o+2] + zr[o+6], ci = zi[o+2] + zi[o+6];
        float dr = zi[o+2] - zi[o+6], di = -(zr[o+2] - zr[o+6]);
        zr[o]   = ar + cr; zi[o]   = ai + ci;
        zr[o+2] = br + dr; zi[o+2] = bi + di;
        zr[o+4] = ar - cr; zi[o+4] = ai - ci;
        zr[o+6] = br - dr; zi[o+6] = bi - di;
    }
    {
        float ar = zr[o+1] + zr[o+5], ai = zi[o+1] + zi[o+5];
        float br = zr[o+1] - zr[o+5], bi = zi[o+1] - zi[o+5];
        float cr = zr[o+3] + zr[o+7], ci = zi[o+3] + zi[o+7];
        float dr = zi[o+3] - zi[o+7], di = -(zr[o+3] - zr[o+7]);
        zr[o+1] = ar + cr; zi[o+1] = ai + ci;
        float t1r = br + dr, t1i = bi + di;
        zr[o+3] = R * (t1r + t1i); zi[o+3] = R * (t1i - t1r);
        float t2r = ar - cr, t2i = ai - ci;
        zr[o+5] = t2i;  zi[o+5] = -t2r;
        float t3r = br - dr, t3i = bi - di;
        zr[o+7] = R * (t3i - t3r); zi[o+7] = -R * (t3r + t3i);
    }
#pragma unroll
    for (int p = 0; p < 8; p += 2) {
        float ur = zr[o+p], ui = zi[o+p], vr = zr[o+p+1], vi = zi[o+p+1];
        zr[o+p]   = ur + vr; zi[o+p]   = ui + vi;
        zr[o+p+1] = ur - vr; zi[o+p+1] = ui - vi;
    }
}

__device__ inline void inv8(float* zr, float* zi, int o)
{
    const float R = 0.70710678118654752f;
#pragma unroll
    for (int p = 0; p < 8; p += 2) {
        float ur = zr[o+p], ui = zi[o+p], vr = zr[o+p+1], vi = zi[o+p+1];
        zr[o+p]   = ur + vr; zi[o+p]   = ui + vi;
        zr[o+p+1] = ur - vr; zi[o+p+1] = ui - vi;
    }
    {
        float t0r = zr[o],   t0i = zi[o];
        float t1r = zr[o+2], t1i = zi[o+2];
        float t2r = zr[o+4], t2i = zi[o+4];
        float t3r = zr[o+6], t3i = zi[o+6];
        float pr = t0r + t2r, pi = t0i + t2i;
        float qr = t0r - t2r, qi = t0i - t2i;
        float rr = t1r + t3r, ri = t1i + t3i;
        float sr = -(t1i - t3i), si = t1r - t3r;
        zr[o]   = pr + rr; zi[o]   = pi + ri;
        zr[o+2] = qr + sr; zi[o+2] = qi + si;
        zr[o+4] = pr - rr; zi[o+4] = pi - ri;
        zr[o+6] = qr - sr; zi[o+6] = qi - si;
    }
    {
        float t0r = zr[o+1], t0i = zi[o+1];
        float yr = zr[o+3], yi = zi[o+3];
        float t1r = R * (yr - yi), t1i = R * (yr + yi);
        yr = zr[o+5]; yi = zi[o+5];
        float t2r = -yi, t2i = yr;
        yr = zr[o+7]; yi = zi[o+7];
        float t3r = -R * (yr + yi), t3i = R * (yr - yi);
        float pr = t0r + t2r, pi = t0i + t2i;
        float qr = t0r - t2r, qi = t0i - t2i;
        float rr = t1r + t3r, ri = t1i + t3i;
        float sr = -(t1i - t3i), si = t1r - t3r;
        zr[o+1] = pr + rr; zi[o+1] = pi + ri;
        zr[o+3] = qr + sr; zi[o+3] = qi + si;
        zr[o+5] = pr - rr; zi[o+5] = pi - ri;
        zr[o+7] = qr - sr; zi[o+7] = qi - si;
    }
}

// ============ prep (REVERTED to R8 = empirical best ~38us, total 144.2):
//   [blocks 0..255] RPE (32 pos/block, all 512 outputs) -> a_t
//   [blocks 256..767] transpose x -> xt2 ============
__global__ __launch_bounds__(512, 4) void prep_kernel(
    const float* __restrict__ x,
    const float* __restrict__ w_in, const float* __restrict__ b_in,
    const float* __restrict__ w_hid, const float* __restrict__ b_hid,
    const float* __restrict__ w_out, const float* __restrict__ b_out,
    float* __restrict__ a_t, float2* __restrict__ xt2)
{
    __shared__ __align__(16) char smem[43264];
    const int tid = threadIdx.x;

    if (blockIdx.x >= 256) {
        float (*t0)[65] = (float (*)[65])smem;
        float (*t1)[65] = (float (*)[65])(smem + 16640);
        int bb = blockIdx.x - 256;
        int h = bb >> 6;
        int nb = bb & 63;
        int lx = tid & 63;
        int ly = tid >> 6;          // 0..7
        const float* s0 = x + ((size_t)h * N_SEQ + nb * 64) * 64;
        const float* s1 = x + ((size_t)(8 + h) * N_SEQ + nb * 64) * 64;
        for (int r = ly; r < 64; r += 8) {
            t0[r][lx] = s0[r * 64 + lx];
            t1[r][lx] = s1[r * 64 + lx];
        }
        __syncthreads();
        for (int r = ly; r < 64; r += 8) {
            float2* dst = xt2 + (size_t)(h * 64 + r) * N_SEQ + nb * 64;
            dst[lx] = make_float2(t0[lx][r], t1[lx][r]);
        }
        return;
    }

    float (*ubuf)[65] = (float (*)[65])smem;               // [pos][feat]
    float (*sums)[17] = (float (*)[17])(smem + 8320);
    float4* wl        = (float4*)(smem + 10496);           // weight area

    // ---- hidden chain: thread = (p = tid&31, s = tid>>5 feature-quad) ----
    {
        const int p = tid & 31;
        const int s = tid >> 5;       // 0..15
        const int pos = blockIdx.x * 32 + p;
        float v;
        if (pos == 0 || pos == N_SEQ) v = 1.0f;
        else if (pos < N_SEQ)         v = 1.0f / (float)(pos + 1);
        else                          v = -1.0f / (float)(2 * N_SEQ + 1 - pos);

        float h[4];
#pragma unroll
        for (int i = 0; i < 4; ++i) {
            int f = s * 4 + i;
            h[i] = v * w_in[f] + b_in[f];
        }
        for (int L = 0; L < LAYERS; ++L) {
            const float4* wsrc = (const float4*)(w_hid + L * 4096);
            wl[tid] = wsrc[tid];
            wl[tid + 512] = wsrc[tid + 512];
            float s2 = h[0]*h[0] + h[1]*h[1] + h[2]*h[2] + h[3]*h[3];
            sums[p][s] = s2;
            __syncthreads();
            float tot = 0.f;
#pragma unroll
            for (int g = 0; g < 16; ++g) tot += sums[p][g];
            float r = rsqrtf(tot * (1.f / 64.f) + 1e-8f);
#pragma unroll
            for (int i = 0; i < 4; ++i)
                ubuf[p][s * 4 + i] = fmaxf(h[i] * r, 0.f);
            __syncthreads();
            float acc[4];
#pragma unroll
            for (int i = 0; i < 4; ++i) acc[i] = b_hid[L * 64 + s * 4 + i];
#pragma unroll 8
            for (int j = 0; j < 64; ++j) {
                float uj = ubuf[p][j];
                float4 w = wl[j * 16 + s];
                acc[0] = fmaf(uj, w.x, acc[0]); acc[1] = fmaf(uj, w.y, acc[1]);
                acc[2] = fmaf(uj, w.z, acc[2]); acc[3] = fmaf(uj, w.w, acc[3]);
            }
#pragma unroll
            for (int i = 0; i < 4; ++i) h[i] = acc[i];
            __syncthreads();
        }
        float s2 = h[0]*h[0] + h[1]*h[1] + h[2]*h[2] + h[3]*h[3];
        sums[p][s] = s2;
        __syncthreads();
        float tot = 0.f;
#pragma unroll
        for (int g = 0; g < 16; ++g) tot += sums[p][g];
        float r = rsqrtf(tot * (1.f / 64.f) + 1e-8f);
#pragma unroll
        for (int i = 0; i < 4; ++i)
            ubuf[p][s * 4 + i] = fmaxf(h[i] * r, 0.f);
        __syncthreads();
    }

    // ---- out GEMM: thread = (o = tid>>3 octet, pg = tid&7 pos-group of 4) ----
    {
        const int o  = tid >> 3;
        const int pg = tid & 7;
        const int pos0 = blockIdx.x * 32;
        float4* wt = wl;               // [16][128] float4
        float acc[8][4];
#pragma unroll
        for (int ii = 0; ii < 8; ++ii) {
            float bo = b_out[o * 8 + ii];
#pragma unroll
            for (int i = 0; i < 4; ++i) acc[ii][i] = bo;
        }
        for (int jc = 0; jc < 4; ++jc) {
            float4 wreg[4];
#pragma unroll
            for (int k = 0; k < 4; ++k) {
                int i4 = k * 512 + tid;
                int jj = i4 >> 7, f4 = i4 & 127;
                wreg[k] = *(const float4*)(w_out + (jc * 16 + jj) * 512 + f4 * 4);
            }
            __syncthreads();
#pragma unroll
            for (int k = 0; k < 4; ++k) {
                int i4 = k * 512 + tid;
                wt[i4] = wreg[k];
            }
            __syncthreads();
#pragma unroll
            for (int jj = 0; jj < 16; ++jj) {
                int j = jc * 16 + jj;
                float4 w0 = wt[jj * 128 + o * 2];
                float4 w1 = wt[jj * 128 + o * 2 + 1];
                float u0 = ubuf[pg * 4 + 0][j];
                float u1 = ubuf[pg * 4 + 1][j];
                float u2 = ubuf[pg * 4 + 2][j];
                float u3 = ubuf[pg * 4 + 3][j];
                acc[0][0] = fmaf(u0, w0.x, acc[0][0]); acc[0][1] = fmaf(u1, w0.x, acc[0][1]);
                acc[0][2] = fmaf(u2, w0.x, acc[0][2]); acc[0][3] = fmaf(u3, w0.x, acc[0][3]);
                acc[1][0] = fmaf(u0, w0.y, acc[1][0]); acc[1][1] = fmaf(u1, w0.y, acc[1][1]);
                acc[1][2] = fmaf(u2, w0.y, acc[1][2]); acc[1][3] = fmaf(u3, w0.y, acc[1][3]);
                acc[2][0] = fmaf(u0, w0.z, acc[2][0]); acc[2][1] = fmaf(u1, w0.z, acc[2][1]);
                acc[2][2] = fmaf(u2, w0.z, acc[2][2]); acc[2][3] = fmaf(u3, w0.z, acc[2][3]);
                acc[3][0] = fmaf(u0, w0.w, acc[3][0]); acc[3][1] = fmaf(u1, w0.w, acc[3][1]);
                acc[3][2] = fmaf(u2, w0.w, acc[3][2]); acc[3][3] = fmaf(u3, w0.w, acc[3][3]);
                acc[4][0] = fmaf(u0, w1.x, acc[4][0]); acc[4][1] = fmaf(u1, w1.x, acc[4][1]);
                acc[4][2] = fmaf(u2, w1.x, acc[4][2]); acc[4][3] = fmaf(u3, w1.x, acc[4][3]);
                acc[5][0] = fmaf(u0, w1.y, acc[5][0]); acc[5][1] = fmaf(u1, w1.y, acc[5][1]);
                acc[5][2] = fmaf(u2, w1.y, acc[5][2]); acc[5][3] = fmaf(u3, w1.y, acc[5][3]);
                acc[6][0] = fmaf(u0, w1.z, acc[6][0]); acc[6][1] = fmaf(u1, w1.z, acc[6][1]);
                acc[6][2] = fmaf(u2, w1.z, acc[6][2]); acc[6][3] = fmaf(u3, w1.z, acc[6][3]);
                acc[7][0] = fmaf(u0, w1.w, acc[7][0]); acc[7][1] = fmaf(u1, w1.w, acc[7][1]);
                acc[7][2] = fmaf(u2, w1.w, acc[7][2]); acc[7][3] = fmaf(u3, w1.w, acc[7][3]);
            }
            __syncthreads();
        }
#pragma unroll
        for (int ii = 0; ii < 8; ++ii) {
            int f = o * 8 + ii;
#pragma unroll
            for (int i = 0; i < 4; ++i)
                a_t[(size_t)f * N_FFT + pos0 + pg * 4 + i] = acc[ii][i];
        }
    }
}

// ========== conv: interleaved-complex LDS; A-FFT (regs) + z-FFT + mult + iFFT ==========
__global__ __launch_bounds__(FT, 2) void conv_kernel(const float* __restrict__ a_t,
                                                     const float2* __restrict__ xt2,
                                                     float2* __restrict__ out_t2)
{
    __shared__ float2 z[8704];   // 8192 + pads = 69632 B
    const int tid = threadIdx.x;
    const int hd = blockIdx.x;
    const float JR = 0.9238795325f;        // e^{-2pi i/16}
    const float JI = -0.3826834324f;

    // ---- A forward: fused m=8192 stage (real input) ----
    {
        const float* src = a_t + (size_t)hd * N_FFT;
        float ck, sk;
        __sincosf(-6.283185307179586f / 8192.f * (float)tid, &sk, &ck);
#pragma unroll
        for (int pp = 0; pp < 4; ++pp) {
            int k = pp * FT + tid;
            float x0 = src[k], x1 = src[k + 2048], x2 = src[k + 4096], x3 = src[k + 6144];
            float ar = x0 + x2, br = x0 - x2;
            float cr = x1 + x3, e = x1 - x3;
            z[PZ(k)] = make_float2(ar + cr, 0.f);
            float c1 = ck, s1 = sk;
            float c2 = c1 * c1 - s1 * s1, s2 = 2.f * c1 * s1;
            float c3 = c2 * c1 - s2 * s1, s3 = c2 * s1 + s2 * c1;
            z[PZ(k + 2048)] = make_float2(br * c1 + e * s1, br * s1 - e * c1);
            float t2r = ar - cr;
            z[PZ(k + 4096)] = make_float2(t2r * c2, t2r * s2);
            z[PZ(k + 6144)] = make_float2(br * c3 - e * s3, br * s3 + e * c3);
            float tc = ck * JR - sk * JI; sk = ck * JI + sk * JR; ck = tc;  // W^{k+512}
        }
    }
    __syncthreads();
    pass16z_fwd<2048>(z, tid);
    __syncthreads();
    pass16z_fwd<128>(z, tid);
    __syncthreads();
    // ---- A tail: unscaled spectrum stays in registers ----
    float afr[16], afi[16];
    {
        const int base = tid * 16;
#pragma unroll
        for (int c = 0; c < 16; ++c) { float2 v = z[PZ(base + c)]; afr[c] = v.x; afi[c] = v.y; }
        fwd8(afr, afi, 0); fwd8(afr, afi, 8);
    }
    __syncthreads();
    // ---- Z forward: fused m=8192 stage (packed complex, x2=x3=0) ----
    {
        const float2* src = xt2 + (size_t)hd * N_SEQ;
        float ck, sk;
        __sincosf(-6.283185307179586f / 8192.f * (float)tid, &sk, &ck);
#pragma unroll
        for (int pp = 0; pp < 4; ++pp) {
            int k = pp * FT + tid;
            float2 z0 = src[k], z1 = src[k + 2048];
            float ar = z0.x, ai = z0.y;
            float cr = z1.x, ci = z1.y;
            float dr = z1.y, di = -z1.x;
            z[PZ(k)] = make_float2(ar + cr, ai + ci);
            float c1 = ck, s1 = sk;
            float c2 = c1 * c1 - s1 * s1, s2 = 2.f * c1 * s1;
            float c3 = c2 * c1 - s2 * s1, s3 = c2 * s1 + s2 * c1;
            float t1r = ar + dr, t1i = ai + di;
            z[PZ(k + 2048)] = make_float2(t1r * c1 - t1i * s1, t1r * s1 + t1i * c1);
            float t2r = ar - cr, t2i = ai - ci;
            z[PZ(k + 4096)] = make_float2(t2r * c2 - t2i * s2, t2r * s2 + t2i * c2);
            float t3r = ar - dr, t3i = ai - di;
            z[PZ(k + 6144)] = make_float2(t3r * c3 - t3i * s3, t3r * s3 + t3i * c3);
            float tc = ck * JR - sk * JI; sk = ck * JI + sk * JR; ck = tc;
        }
    }
    __syncthreads();
    pass16z_fwd<2048>(z, tid);
    __syncthreads();
    pass16z_fwd<128>(z, tid);
    __syncthreads();
    {   // Z tail + pointwise (af in regs, 1/N fused) + inverse head
        const int base = tid * 16;
        float zr[16], zi[16];
#pragma unroll
        for (int c = 0; c < 16; ++c) { float2 v = z[PZ(base + c)]; zr[c] = v.x; zi[c] = v.y; }
        fwd8(zr, zi, 0); fwd8(zr, zi, 8);
        const float inv = 1.0f / (float)N_FFT;
#pragma unroll
        for (int c = 0; c < 16; ++c) {
            float xr = zr[c], xi_ = zi[c];
            zr[c] = (xr * afr[c] - xi_ * afi[c]) * inv;
            zi[c] = (xr * afi[c] + xi_ * afr[c]) * inv;
        }
        inv8(zr, zi, 0); inv8(zr, zi, 8);
#pragma unroll
        for (int c = 0; c < 16; ++c) z[PZ(base + c)] = make_float2(zr[c], zi[c]);
    }
    __syncthreads();
    pass16z_inv<128>(z, tid);
    __syncthreads();
    pass16z_inv<2048>(z, tid);
    __syncthreads();
    {   // fused final inverse stage (m=8192): store only [0,4096)
        float2* dst = out_t2 + (size_t)hd * N_SEQ;
        float ck, sk;
        __sincosf(6.283185307179586f / 8192.f * (float)tid, &sk, &ck);
        const float JcR = 0.9238795325f, JcI = 0.3826834324f;
#pragma unroll
        for (int pp = 0; pp < 4; ++pp) {
            int k = pp * FT + tid;
            float c1 = ck, s1 = sk;
            float c2 = c1 * c1 - s1 * s1, s2 = 2.f * c1 * s1;
            float c3 = c2 * c1 - s2 * s1, s3 = c2 * s1 + s2 * c1;
            float2 y0 = z[PZ(k)];
            float2 y1 = z[PZ(k + 2048)];
            float2 y2 = z[PZ(k + 4096)];
            float2 y3 = z[PZ(k + 6144)];
            float t0r = y0.x, t0i = y0.y;
            float t1r = y1.x * c1 - y1.y * s1, t1i = y1.x * s1 + y1.y * c1;
            float t2r = y2.x * c2 - y2.y * s2, t2i = y2.x * s2 + y2.y * c2;
            float t3r = y3.x * c3 - y3.y * s3, t3i = y3.x * s3 + y3.y * c3;
            float pr = t0r + t2r, pi = t0i + t2i;
            float qr = t0r - t2r, qi = t0i - t2i;
            float rr = t1r + t3r, ri = t1i + t3i;
            float sr = -(t1i - t3i), si = t1r - t3r;
            dst[k]        = make_float2(pr + rr, pi + ri);
            dst[k + 2048] = make_float2(qr + sr, qi + si);
            float tc = ck * JcR - sk * JcI; sk = ck * JcI + sk * JcR; ck = tc;
        }
    }
}

// ========== transpose out: out_t2[hd][n] -> out (2,8,N,64) ==========
__global__ __launch_bounds__(256) void transpose_o_kernel(const float2* __restrict__ out_t2,
                                                          float* __restrict__ out)
{
    __shared__ float t0[64][65];
    __shared__ float t1[64][65];
    int h = blockIdx.x >> 6;
    int nb = blockIdx.x & 63;
    int lx = threadIdx.x & 63;
    int ly = threadIdx.x >> 6;
    for (int r = ly; r < 64; r += 4) {
        float2 v = out_t2[(size_t)(h * 64 + r) * N_SEQ + nb * 64 + lx];
        t0[r][lx] = v.x;
        t1[r][lx] = v.y;
    }
    __syncthreads();
    float* d0 = out + ((size_t)h * N_SEQ + nb * 64) * 64;
    float* d1 = out + ((size_t)(8 + h) * N_SEQ + nb * 64) * 64;
    for (int r = ly; r < 64; r += 4) {
        d0[r * 64 + lx] = t0[lx][r];
        d1[r * 64 + lx] = t1[lx][r];
    }
}

extern "C" void kernel_launch(void* const* d_in, const int* in_sizes, int n_in,
                              void* d_out, int out_size, void* d_ws, size_t ws_size,
                              hipStream_t stream)
{
    const float* x     = (const float*)d_in[0];
    const float* w_in  = (const float*)d_in[1];
    const float* b_in  = (const float*)d_in[2];
    const float* w_hid = (const float*)d_in[3];
    const float* b_hid = (const float*)d_in[4];
    const float* w_out = (const float*)d_in[5];
    const float* b_out = (const float*)d_in[6];
    float* out = (float*)d_out;

    char* ws = (char*)d_ws;
    float2* xt2    = (float2*)ws;                               // 16 MB
    float*  a_t    = (float*)(ws + (size_t)16 * 1024 * 1024);   // 16 MB
    float2* out_t2 = (float2*)(ws + (size_t)32 * 1024 * 1024);  // 16 MB

    prep_kernel<<<768, 512, 0, stream>>>(x, w_in, b_in, w_hid, b_hid, w_out, b_out,
                                         a_t, xt2);
    conv_kernel<<<512, FT, 0, stream>>>(a_t, xt2, out_t2);
    transpose_o_kernel<<<512, 256, 0, stream>>>(out_t2, out);
}